// Round 4
// baseline (1602.687 us; speedup 1.0000x reference)
//
#include <hip/hip_runtime.h>

// spatialAttentionScaledGCN — MI355X MFMA, round 4: occupancy + latency overlap.
// B=8, N=512, T=12, F=32, O=64. All I/O fp32.
// Per (b,t): S = X_t·X_tᵀ·inv_f (mfma 16x16x32_f16, K=32, single instr),
// softmax WITHOUT max-pass (scores bounded; clamp 60), cross-wave row-sum via
// ds_add + lgkm-only barrier (global prefetches stay in flight across it),
// W = e·inv_f/Σ·phase in regs (score C-layout ≡ B-layout of W),
// x_predᵀ += Xpᵀ·W (mfma 16x16x16f16 flipped → 4 consecutive f per lane →
// pk_add_f32 v2 atomics). MT=8 m-splits, grid 704/768 blocks.

#define B_ 8
#define N_ 512
#define T_ 12
#define F_ 32
#define O_ 64
#define MT 8                     // m-splits per (b,t); block owns 64 m-rows

typedef unsigned int uint_t;
typedef unsigned short ushort_t;
typedef _Float16 f16_t;
typedef _Float16 f16x4 __attribute__((ext_vector_type(4)));
typedef _Float16 f16x8 __attribute__((ext_vector_type(8)));
typedef float f32x4 __attribute__((ext_vector_type(4)));
typedef float f32x2 __attribute__((ext_vector_type(2)));

__device__ __forceinline__ void atomAddF(float* p, float v) {
    __hip_atomic_fetch_add(p, v, __ATOMIC_RELAXED, __HIP_MEMORY_SCOPE_AGENT);
}
#if __has_builtin(__builtin_amdgcn_global_atomic_fadd_v2f32)
typedef __attribute__((address_space(1))) f32x2 f32x2_as1;
__device__ __forceinline__ void atomAdd2(float* p, float a, float b) {
    __builtin_amdgcn_global_atomic_fadd_v2f32((f32x2_as1*)(unsigned long long)p,
                                              (f32x2){a, b});
}
#else
__device__ __forceinline__ void atomAdd2(float* p, float a, float b) {
    atomAddF(p, a); atomAddF(p + 1, b);
}
#endif

// barrier with LDS-only drain: global loads stay in flight (unlike __syncthreads,
// which emits s_waitcnt vmcnt(0) and kills cross-barrier prefetch)
#define LGKM_BARRIER() asm volatile("s_waitcnt lgkmcnt(0)\n\ts_barrier" ::: "memory")

__device__ __forceinline__ int xidx(int b, int n, int t, int f) {
    return ((b * N_ + n) * T_ + t) * F_ + f;
}
__device__ __forceinline__ f16x8 load_frag8(const float* p) {
    float4 a = *reinterpret_cast<const float4*>(p);
    float4 b = *reinterpret_cast<const float4*>(p + 4);
    f16x8 r;
    r[0] = (f16_t)a.x; r[1] = (f16_t)a.y; r[2] = (f16_t)a.z; r[3] = (f16_t)a.w;
    r[4] = (f16_t)b.x; r[5] = (f16_t)b.y; r[6] = (f16_t)b.z; r[7] = (f16_t)b.w;
    return r;
}
union U2H4 { uint2 u; f16x4 h; };

// ---------------------------------------------------------------------------
// Permute one 512x512 fp32 slice into MFMA-lane-order fp16 (same as R3).
__global__ __launch_bounds__(256)
void permute_kernel(const float* __restrict__ src, ushort_t* __restrict__ dst)
{
    __shared__ float Lp[16][516];
    const int tid = threadIdx.x;
    const int mc  = blockIdx.x;               // 0..31 row-chunk
    const int s   = blockIdx.y;               // slice
    src += (size_t)s * N_ * N_ + (size_t)mc * 16 * N_;
    uint_t* dstu = (uint_t*)dst + (size_t)s * 131072 + (size_t)mc * 4096;

    #pragma unroll
    for (int k = 0; k < 32; ++k) {
        int idx = tid + 256 * k;
        Lp[idx >> 9][idx & 511] = src[idx];
    }
    __syncthreads();
    #pragma unroll
    for (int k = 0; k < 16; ++k) {
        int u    = tid + 256 * k;
        int nt   = u >> 7;
        int r    = u & 127;
        int quad = r >> 5;
        int cl   = (r >> 1) & 15;
        int m0   = quad * 4 + (r & 1) * 2;
        int n    = nt * 16 + cl;
        union { f16_t h[2]; uint_t i; } pk;
        pk.h[0] = (f16_t)Lp[m0][n];
        pk.h[1] = (f16_t)Lp[m0 + 1][n];
        dstu[u] = pk.i;
    }
}

// ---------------------------------------------------------------------------
template <int FINAL>
__global__ __launch_bounds__(512)
void gcn_kernel(const float* __restrict__ x0,
                const float* __restrict__ xcur,
                float* __restrict__ dst,            // xnext or agg (pre-zeroed)
                const ushort_t* __restrict__ phase_h,
                const ushort_t* __restrict__ adj_h,
                const float* __restrict__ mask)
{
    __shared__ float st[4][16];                     // per-chunk row sums

    const int tid  = threadIdx.x;
    const int w    = tid >> 6;
    const int l    = tid & 63;
    const int quad = l >> 4;
    const int col  = l & 15;
    const int mt   = blockIdx.x;                    // 0..7
    const int t    = FINAL ? blockIdx.y : blockIdx.y + 1;
    const int b    = blockIdx.z;
    const int nt0  = w * 4;                         // wave owns n-tiles nt0..nt0+3
    const float inv_f = 0.17677669529663687f;

    const float* xs = (FINAL && t == 0) ? x0 : xcur;
    const float* xp = FINAL ? xs : ((t == 1) ? x0 : xcur);
    const int    tp = FINAL ? t : t - 1;

    if (tid < 64) ((float*)st)[tid] = 0.f;

    // score B-frags (fixed across chunks)
    f16x8 bf[4];
    #pragma unroll
    for (int i = 0; i < 4; ++i)
        bf[i] = load_frag8(&xs[xidx(b, (nt0 + i) * 16 + col, t, quad * 8)]);

    const uint_t* phu = (const uint_t*)phase_h + (size_t)(b * T_ + t) * 131072;
    const uint_t* adu = (const uint_t*)adj_h;

    // prefetch chunk 0 operands
    f16x8 af = load_frag8(&xs[xidx(b, mt * 64 + col, t, quad * 8)]);
    f16x4 bp[2];
    #pragma unroll
    for (int fh = 0; fh < 2; ++fh)
        #pragma unroll
        for (int j = 0; j < 4; ++j)
            bp[fh][j] = (f16_t)xp[xidx(b, mt * 64 + quad * 4 + j, tp, fh * 16 + col)];
    uint2 ph[4], aj[4];
    #pragma unroll
    for (int i = 0; i < 4; ++i) {
        ph[i] = *(const uint2*)(phu + (size_t)(mt * 4) * 4096 + (nt0 + i) * 128 + l * 2);
        if (FINAL)
            aj[i] = *(const uint2*)(adu + (size_t)(mt * 4) * 4096 + (nt0 + i) * 128 + l * 2);
    }

    f32x4 acc[4][2];
    #pragma unroll
    for (int i = 0; i < 4; ++i) {
        acc[i][0] = (f32x4){0.f, 0.f, 0.f, 0.f};
        acc[i][1] = (f32x4){0.f, 0.f, 0.f, 0.f};
    }

    LGKM_BARRIER();                                 // st zeros visible

    for (int c = 0; c < 4; ++c) {                   // 4 chunks of 16 m-rows
        // ---- score MFMAs ----
        f32x4 s4[4];
        #pragma unroll
        for (int i = 0; i < 4; ++i)
            s4[i] = __builtin_amdgcn_mfma_f32_16x16x32_f16(
                        af, bf[i], (f32x4){0.f, 0.f, 0.f, 0.f}, 0, 0, 0);

        // ---- prefetch chunk c+1 (overlaps softmax; survives LGKM_BARRIER) ----
        const int c2  = (c < 3) ? c + 1 : c;
        const int mb2 = mt * 64 + c2 * 16;
        f16x8 af_n = load_frag8(&xs[xidx(b, mb2 + col, t, quad * 8)]);
        f16x4 bp_n[2];
        #pragma unroll
        for (int fh = 0; fh < 2; ++fh)
            #pragma unroll
            for (int j = 0; j < 4; ++j)
                bp_n[fh][j] = (f16_t)xp[xidx(b, mb2 + quad * 4 + j, tp, fh * 16 + col)];
        uint2 ph_n[4], aj_n[4];
        #pragma unroll
        for (int i = 0; i < 4; ++i) {
            ph_n[i] = *(const uint2*)(phu + (size_t)(mt * 4 + c2) * 4096 + (nt0 + i) * 128 + l * 2);
            if (FINAL)
                aj_n[i] = *(const uint2*)(adu + (size_t)(mt * 4 + c2) * 4096 + (nt0 + i) * 128 + l * 2);
        }

        // ---- e = exp(s·inv_f) (no max pass; scores bounded, clamp for safety) ----
        float e[4][4], sw[4];
        #pragma unroll
        for (int v = 0; v < 4; ++v) {
            #pragma unroll
            for (int i = 0; i < 4; ++i)
                e[i][v] = __expf(fminf(s4[i][v] * inv_f, 60.f));
            sw[v] = (e[0][v] + e[1][v]) + (e[2][v] + e[3][v]);
        }
        #pragma unroll
        for (int d = 1; d < 16; d <<= 1)
            #pragma unroll
            for (int v = 0; v < 4; ++v)
                sw[v] += __shfl_xor(sw[v], d, 64);
        if (col < 4) {
            float sv = (col == 0) ? sw[0] : (col == 1) ? sw[1] : (col == 2) ? sw[2] : sw[3];
            atomicAdd(&st[c][quad * 4 + col], sv);  // ds_add, 8 waves/row
        }

        // ---- fold phase (and adj) while barrier pends ----
        #pragma unroll
        for (int i = 0; i < 4; ++i) {
            U2H4 P; P.u = ph[i];
            if (FINAL) {
                U2H4 A; A.u = aj[i];
                #pragma unroll
                for (int v = 0; v < 4; ++v) e[i][v] *= (float)P.h[v] * (float)A.h[v];
            } else {
                #pragma unroll
                for (int v = 0; v < 4; ++v) e[i][v] *= (float)P.h[v];
            }
        }

        LGKM_BARRIER();

        // ---- normalize + pred MFMAs (flipped: Y = Xpᵀ·W, rows = f) ----
        f32x4 rs = *(const f32x4*)&st[c][quad * 4];
        f32x4 bet;
        #pragma unroll
        for (int v = 0; v < 4; ++v) bet[v] = inv_f * __builtin_amdgcn_rcpf(rs[v]);
        #pragma unroll
        for (int i = 0; i < 4; ++i) {
            f16x4 wf;
            #pragma unroll
            for (int v = 0; v < 4; ++v) wf[v] = (f16_t)(e[i][v] * bet[v]);
            #pragma unroll
            for (int fh = 0; fh < 2; ++fh)
                acc[i][fh] = __builtin_amdgcn_mfma_f32_16x16x16f16(bp[fh], wf, acc[i][fh], 0, 0, 0);
        }

        af = af_n;
        bp[0] = bp_n[0]; bp[1] = bp_n[1];
        #pragma unroll
        for (int i = 0; i < 4; ++i) { ph[i] = ph_n[i]; if (FINAL) aj[i] = aj_n[i]; }
    }

    // ---- epilogue: lane holds Y[f = fh*16+quad*4+v][n = (nt0+i)*16+col] ----
    #pragma unroll
    for (int i = 0; i < 4; ++i) {
        const int n = (nt0 + i) * 16 + col;
        const bool go = FINAL ? true : (mask[n] == 0.f);
        if (go) {
            float* d0 = FINAL ? &dst[((b * T_ + t) * N_ + n) * F_]
                              : &dst[xidx(b, n, t, 0)];
            #pragma unroll
            for (int fh = 0; fh < 2; ++fh) {
                float* p = d0 + fh * 16 + quad * 4;
                atomAdd2(p,     acc[i][fh][0], acc[i][fh][1]);
                atomAdd2(p + 2, acc[i][fh][2], acc[i][fh][3]);
            }
        }
    }
    if (!FINAL && mt == 0) {                        // masked passthrough
        for (int p = tid; p < N_ * F_; p += 512) {
            int n = p >> 5, f = p & 31;
            if (mask[n] != 0.f) dst[xidx(b, n, t, f)] = xcur[xidx(b, n, t, f)];
        }
    }
}

// out[b,n,t,o] = relu(sum_f agg[b,t,n,f] * theta[f,o])
__global__ __launch_bounds__(256)
void proj_kernel(const float* __restrict__ agg, const float* __restrict__ theta,
                 float* __restrict__ out)
{
    __shared__ float th[F_ * O_];
    int tid = threadIdx.x;
    #pragma unroll
    for (int p = 0; p < 8; ++p) th[tid + 256 * p] = theta[tid + 256 * p];
    __syncthreads();
    int g  = blockIdx.x * 256 + tid;               // ((b*N+n)*T+t)*O+o
    int o  = g & 63;
    int r  = g >> 6;
    int tt = r % T_;
    int r2 = r / T_;
    int n  = r2 & 511;
    int b  = r2 >> 9;
    const float* a = &agg[((b * T_ + tt) * N_ + n) * F_];
    float s = 0.f;
    #pragma unroll
    for (int f = 0; f < F_; ++f) s += a[f] * th[f * O_ + o];
    out[g] = fmaxf(s, 0.f);
}

extern "C" void kernel_launch(void* const* d_in, const int* in_sizes, int n_in,
                              void* d_out, int out_size, void* d_ws, size_t ws_size,
                              hipStream_t stream)
{
    const float* x     = (const float*)d_in[0];
    const float* phase = (const float*)d_in[1];
    const float* adj   = (const float*)d_in[2];
    const float* mask  = (const float*)d_in[3];
    const float* theta = (const float*)d_in[4];
    float* out = (float*)d_out;

    const size_t XE = (size_t)B_ * N_ * T_ * F_;        // 1,572,864 floats
    float*    bufs    = (float*)d_ws;                   // 11 iter outputs + agg
    float*    agg     = bufs + (size_t)11 * XE;
    ushort_t* phase_h = (ushort_t*)(bufs + (size_t)12 * XE);  // 96 slices f16
    ushort_t* adj_h   = phase_h + (size_t)96 * N_ * N_;

    // one zero-fill for all 12 atomic-destination buffers (75.5 MB)
    hipMemsetAsync(bufs, 0, (size_t)12 * XE * sizeof(float), stream);
    permute_kernel<<<dim3(32, 96), 256, 0, stream>>>(phase, phase_h);
    permute_kernel<<<dim3(32, 1), 256, 0, stream>>>(adj, adj_h);

    const float* cur = x;
    for (int i = 0; i < T_ - 1; ++i) {                  // 11 Jacobi iterations
        float* nxt = bufs + (size_t)i * XE;
        gcn_kernel<0><<<dim3(MT, T_ - 1, B_), 512, 0, stream>>>(
            x, cur, nxt, phase_h, adj_h, mask);
        cur = nxt;
    }
    gcn_kernel<1><<<dim3(MT, T_, B_), 512, 0, stream>>>(
        x, cur, agg, phase_h, adj_h, mask);
    proj_kernel<<<(B_ * N_ * T_ * O_) / 256, 256, 0, stream>>>(agg, theta, out);
}

// Round 5
// 1091.068 us; speedup vs baseline: 1.4689x; 1.4689x over previous
//
#include <hip/hip_runtime.h>

// spatialAttentionScaledGCN — MI355X MFMA, round 5.
// R4 latency structure (MT=8, no-max softmax, ds_add rowsum, lgkm-only
// barriers, cross-barrier prefetch) + R3's coalescing-friendly pred MFMA
// orientation and plain 4B agent-scope atomics (the pk_add_v2f32 path
// bypassed L2: 192 MB HBM writes/dispatch vs 13.9 MB with dword atomics).

#define B_ 8
#define N_ 512
#define T_ 12
#define F_ 32
#define O_ 64
#define MT 8                     // m-splits per (b,t); block owns 64 m-rows

typedef unsigned int uint_t;
typedef unsigned short ushort_t;
typedef _Float16 f16_t;
typedef _Float16 f16x4 __attribute__((ext_vector_type(4)));
typedef _Float16 f16x8 __attribute__((ext_vector_type(8)));
typedef float f32x4 __attribute__((ext_vector_type(4)));

__device__ __forceinline__ void atomAddF(float* p, float v) {
    __hip_atomic_fetch_add(p, v, __ATOMIC_RELAXED, __HIP_MEMORY_SCOPE_AGENT);
}

// barrier with LDS-only drain: global loads stay in flight (unlike
// __syncthreads, which emits s_waitcnt vmcnt(0) and kills prefetch)
#define LGKM_BARRIER() asm volatile("s_waitcnt lgkmcnt(0)\n\ts_barrier" ::: "memory")

__device__ __forceinline__ int xidx(int b, int n, int t, int f) {
    return ((b * N_ + n) * T_ + t) * F_ + f;
}
__device__ __forceinline__ f16x8 load_frag8(const float* p) {
    float4 a = *reinterpret_cast<const float4*>(p);
    float4 b = *reinterpret_cast<const float4*>(p + 4);
    f16x8 r;
    r[0] = (f16_t)a.x; r[1] = (f16_t)a.y; r[2] = (f16_t)a.z; r[3] = (f16_t)a.w;
    r[4] = (f16_t)b.x; r[5] = (f16_t)b.y; r[6] = (f16_t)b.z; r[7] = (f16_t)b.w;
    return r;
}
union U2H4 { uint2 u; f16x4 h; };

// ---------------------------------------------------------------------------
// Permute one 512x512 fp32 slice into MFMA-lane-order fp16.
__global__ __launch_bounds__(256)
void permute_kernel(const float* __restrict__ src, ushort_t* __restrict__ dst)
{
    __shared__ float Lp[16][516];
    const int tid = threadIdx.x;
    const int mc  = blockIdx.x;               // 0..31 row-chunk
    const int s   = blockIdx.y;               // slice
    src += (size_t)s * N_ * N_ + (size_t)mc * 16 * N_;
    uint_t* dstu = (uint_t*)dst + (size_t)s * 131072 + (size_t)mc * 4096;

    #pragma unroll
    for (int k = 0; k < 32; ++k) {
        int idx = tid + 256 * k;
        Lp[idx >> 9][idx & 511] = src[idx];
    }
    __syncthreads();
    #pragma unroll
    for (int k = 0; k < 16; ++k) {
        int u    = tid + 256 * k;
        int nt   = u >> 7;
        int r    = u & 127;
        int quad = r >> 5;
        int cl   = (r >> 1) & 15;
        int m0   = quad * 4 + (r & 1) * 2;
        int n    = nt * 16 + cl;
        union { f16_t h[2]; uint_t i; } pk;
        pk.h[0] = (f16_t)Lp[m0][n];
        pk.h[1] = (f16_t)Lp[m0 + 1][n];
        dstu[u] = pk.i;
    }
}

// ---------------------------------------------------------------------------
template <int FINAL>
__global__ __launch_bounds__(512)
void gcn_kernel(const float* __restrict__ x0,
                const float* __restrict__ xcur,
                float* __restrict__ dst,            // xnext or agg (pre-zeroed)
                const ushort_t* __restrict__ phase_h,
                const ushort_t* __restrict__ adj_h,
                const float* __restrict__ mask)
{
    __shared__ float st[4][16];                     // per-chunk row sums

    const int tid  = threadIdx.x;
    const int w    = tid >> 6;
    const int l    = tid & 63;
    const int quad = l >> 4;
    const int col  = l & 15;
    const int mt   = blockIdx.x;                    // 0..7
    const int t    = FINAL ? blockIdx.y : blockIdx.y + 1;
    const int b    = blockIdx.z;
    const int nt0  = w * 4;                         // wave owns n-tiles nt0..nt0+3
    const float inv_f = 0.17677669529663687f;

    const float* xs = (FINAL && t == 0) ? x0 : xcur;
    const float* xp = FINAL ? xs : ((t == 1) ? x0 : xcur);
    const int    tp = FINAL ? t : t - 1;

    if (tid < 64) ((float*)st)[tid] = 0.f;

    // score B-frags (fixed across chunks)
    f16x8 bf[4];
    #pragma unroll
    for (int i = 0; i < 4; ++i)
        bf[i] = load_frag8(&xs[xidx(b, (nt0 + i) * 16 + col, t, quad * 8)]);

    const uint_t* phu = (const uint_t*)phase_h + (size_t)(b * T_ + t) * 131072;
    const uint_t* adu = (const uint_t*)adj_h;

    // prefetch chunk 0 operands
    f16x8 af = load_frag8(&xs[xidx(b, mt * 64 + col, t, quad * 8)]);
    f16x4 bp[2];
    #pragma unroll
    for (int fh = 0; fh < 2; ++fh)
        #pragma unroll
        for (int j = 0; j < 4; ++j)
            bp[fh][j] = (f16_t)xp[xidx(b, mt * 64 + quad * 4 + j, tp, fh * 16 + col)];
    uint2 ph[4], aj[4];
    #pragma unroll
    for (int i = 0; i < 4; ++i) {
        ph[i] = *(const uint2*)(phu + (size_t)(mt * 4) * 4096 + (nt0 + i) * 128 + l * 2);
        if (FINAL)
            aj[i] = *(const uint2*)(adu + (size_t)(mt * 4) * 4096 + (nt0 + i) * 128 + l * 2);
    }

    f32x4 acc[4][2];
    #pragma unroll
    for (int i = 0; i < 4; ++i) {
        acc[i][0] = (f32x4){0.f, 0.f, 0.f, 0.f};
        acc[i][1] = (f32x4){0.f, 0.f, 0.f, 0.f};
    }

    LGKM_BARRIER();                                 // st zeros visible

    for (int c = 0; c < 4; ++c) {                   // 4 chunks of 16 m-rows
        // ---- score MFMAs ----
        f32x4 s4[4];
        #pragma unroll
        for (int i = 0; i < 4; ++i)
            s4[i] = __builtin_amdgcn_mfma_f32_16x16x32_f16(
                        af, bf[i], (f32x4){0.f, 0.f, 0.f, 0.f}, 0, 0, 0);

        // ---- prefetch chunk c+1 (overlaps softmax; survives LGKM_BARRIER) ----
        const int c2  = (c < 3) ? c + 1 : c;
        const int mb2 = mt * 64 + c2 * 16;
        f16x8 af_n = load_frag8(&xs[xidx(b, mb2 + col, t, quad * 8)]);
        f16x4 bp_n[2];
        #pragma unroll
        for (int fh = 0; fh < 2; ++fh)
            #pragma unroll
            for (int j = 0; j < 4; ++j)
                bp_n[fh][j] = (f16_t)xp[xidx(b, mb2 + quad * 4 + j, tp, fh * 16 + col)];
        uint2 ph_n[4], aj_n[4];
        #pragma unroll
        for (int i = 0; i < 4; ++i) {
            ph_n[i] = *(const uint2*)(phu + (size_t)(mt * 4 + c2) * 4096 + (nt0 + i) * 128 + l * 2);
            if (FINAL)
                aj_n[i] = *(const uint2*)(adu + (size_t)(mt * 4 + c2) * 4096 + (nt0 + i) * 128 + l * 2);
        }

        // ---- e = exp(s·inv_f) (no max pass; scores bounded, clamp for safety) ----
        float e[4][4], sw[4];
        #pragma unroll
        for (int v = 0; v < 4; ++v) {
            #pragma unroll
            for (int i = 0; i < 4; ++i)
                e[i][v] = __expf(fminf(s4[i][v] * inv_f, 60.f));
            sw[v] = (e[0][v] + e[1][v]) + (e[2][v] + e[3][v]);
        }
        #pragma unroll
        for (int d = 1; d < 16; d <<= 1)
            #pragma unroll
            for (int v = 0; v < 4; ++v)
                sw[v] += __shfl_xor(sw[v], d, 64);
        if (col < 4) {
            float sv = (col == 0) ? sw[0] : (col == 1) ? sw[1] : (col == 2) ? sw[2] : sw[3];
            atomicAdd(&st[c][quad * 4 + col], sv);  // ds_add, 8 waves/row
        }

        // ---- fold phase (and adj) while barrier pends ----
        #pragma unroll
        for (int i = 0; i < 4; ++i) {
            U2H4 P; P.u = ph[i];
            if (FINAL) {
                U2H4 A; A.u = aj[i];
                #pragma unroll
                for (int v = 0; v < 4; ++v) e[i][v] *= (float)P.h[v] * (float)A.h[v];
            } else {
                #pragma unroll
                for (int v = 0; v < 4; ++v) e[i][v] *= (float)P.h[v];
            }
        }

        LGKM_BARRIER();

        // ---- normalize + pred MFMAs: A = Wᵀ-frag (C-layout), B = Xp ----
        f32x4 rs = *(const f32x4*)&st[c][quad * 4];
        f32x4 bet;
        #pragma unroll
        for (int v = 0; v < 4; ++v) bet[v] = inv_f * __builtin_amdgcn_rcpf(rs[v]);
        #pragma unroll
        for (int i = 0; i < 4; ++i) {
            f16x4 wf;
            #pragma unroll
            for (int v = 0; v < 4; ++v) wf[v] = (f16_t)(e[i][v] * bet[v]);
            #pragma unroll
            for (int fh = 0; fh < 2; ++fh)
                acc[i][fh] = __builtin_amdgcn_mfma_f32_16x16x16f16(wf, bp[fh], acc[i][fh], 0, 0, 0);
        }

        af = af_n;
        bp[0] = bp_n[0]; bp[1] = bp_n[1];
        #pragma unroll
        for (int i = 0; i < 4; ++i) { ph[i] = ph_n[i]; if (FINAL) aj[i] = aj_n[i]; }
    }

    // ---- epilogue: lane holds Y[n=(nt0+i)*16+quad*4+v][f = fh*16+col] ----
    // (16 lanes of a quad cover 16 consecutive f → atomics coalesce per line)
    #pragma unroll
    for (int i = 0; i < 4; ++i) {
        #pragma unroll
        for (int v = 0; v < 4; ++v) {
            const int n = (nt0 + i) * 16 + quad * 4 + v;
            if (FINAL) {
                float* d0 = &dst[((b * T_ + t) * N_ + n) * F_ + col];
                atomAddF(d0,      acc[i][0][v]);
                atomAddF(d0 + 16, acc[i][1][v]);
            } else if (mask[n] == 0.f) {
                atomAddF(&dst[xidx(b, n, t, col)],      acc[i][0][v]);
                atomAddF(&dst[xidx(b, n, t, 16 + col)], acc[i][1][v]);
            }
        }
    }
    if (!FINAL && mt == 0) {                        // masked passthrough
        for (int p = tid; p < N_ * F_; p += 512) {
            int n = p >> 5, f = p & 31;
            if (mask[n] != 0.f) dst[xidx(b, n, t, f)] = xcur[xidx(b, n, t, f)];
        }
    }
}

// out[b,n,t,o] = relu(sum_f agg[b,t,n,f] * theta[f,o])
__global__ __launch_bounds__(256)
void proj_kernel(const float* __restrict__ agg, const float* __restrict__ theta,
                 float* __restrict__ out)
{
    __shared__ float th[F_ * O_];
    int tid = threadIdx.x;
    #pragma unroll
    for (int p = 0; p < 8; ++p) th[tid + 256 * p] = theta[tid + 256 * p];
    __syncthreads();
    int g  = blockIdx.x * 256 + tid;               // ((b*N+n)*T+t)*O+o
    int o  = g & 63;
    int r  = g >> 6;
    int tt = r % T_;
    int r2 = r / T_;
    int n  = r2 & 511;
    int b  = r2 >> 9;
    const float* a = &agg[((b * T_ + tt) * N_ + n) * F_];
    float s = 0.f;
    #pragma unroll
    for (int f = 0; f < F_; ++f) s += a[f] * th[f * O_ + o];
    out[g] = fmaxf(s, 0.f);
}

extern "C" void kernel_launch(void* const* d_in, const int* in_sizes, int n_in,
                              void* d_out, int out_size, void* d_ws, size_t ws_size,
                              hipStream_t stream)
{
    const float* x     = (const float*)d_in[0];
    const float* phase = (const float*)d_in[1];
    const float* adj   = (const float*)d_in[2];
    const float* mask  = (const float*)d_in[3];
    const float* theta = (const float*)d_in[4];
    float* out = (float*)d_out;

    const size_t XE = (size_t)B_ * N_ * T_ * F_;        // 1,572,864 floats
    float*    bufs    = (float*)d_ws;                   // 11 iter outputs + agg
    float*    agg     = bufs + (size_t)11 * XE;
    ushort_t* phase_h = (ushort_t*)(bufs + (size_t)12 * XE);  // 96 slices f16
    ushort_t* adj_h   = phase_h + (size_t)96 * N_ * N_;

    // one zero-fill for all 12 atomic-destination buffers (75.5 MB)
    hipMemsetAsync(bufs, 0, (size_t)12 * XE * sizeof(float), stream);
    permute_kernel<<<dim3(32, 96), 256, 0, stream>>>(phase, phase_h);
    permute_kernel<<<dim3(32, 1), 256, 0, stream>>>(adj, adj_h);

    const float* cur = x;
    for (int i = 0; i < T_ - 1; ++i) {                  // 11 Jacobi iterations
        float* nxt = bufs + (size_t)i * XE;
        gcn_kernel<0><<<dim3(MT, T_ - 1, B_), 512, 0, stream>>>(
            x, cur, nxt, phase_h, adj_h, mask);
        cur = nxt;
    }
    gcn_kernel<1><<<dim3(MT, T_, B_), 512, 0, stream>>>(
        x, cur, agg, phase_h, adj_h, mask);
    proj_kernel<<<(B_ * N_ * T_ * O_) / 256, 256, 0, stream>>>(agg, theta, out);
}

// Round 6
// 1078.888 us; speedup vs baseline: 1.4855x; 1.0113x over previous
//
#include <hip/hip_runtime.h>

// spatialAttentionScaledGCN — MI355X MFMA, round 6: zero-atomic two-phase.
// B=8, N=512, T=12, F=32, O=64. All I/O fp32.
// Per iteration: (1) rowsum kernel: rsinv[b,t,m] = inv_f / sum_n exp(S[m,n]*inv_f)
// (m-split, plain stores); (2) pred kernel: wave owns 16 output n-cols, K-loops
// all 512 m (score MFMA recompute + 2 pred MFMAs/chunk), register accumulate,
// single coalesced store with inline mask blend. No atomics/LDS/barriers/memset.

#define B_ 8
#define N_ 512
#define T_ 12
#define F_ 32
#define O_ 64

typedef unsigned int uint_t;
typedef unsigned short ushort_t;
typedef _Float16 f16_t;
typedef _Float16 f16x4 __attribute__((ext_vector_type(4)));
typedef _Float16 f16x8 __attribute__((ext_vector_type(8)));
typedef float f32x4 __attribute__((ext_vector_type(4)));

__device__ __forceinline__ int xidx(int b, int n, int t, int f) {
    return ((b * N_ + n) * T_ + t) * F_ + f;
}
__device__ __forceinline__ f16x8 load_frag8(const float* p) {
    float4 a = *reinterpret_cast<const float4*>(p);
    float4 b = *reinterpret_cast<const float4*>(p + 4);
    f16x8 r;
    r[0] = (f16_t)a.x; r[1] = (f16_t)a.y; r[2] = (f16_t)a.z; r[3] = (f16_t)a.w;
    r[4] = (f16_t)b.x; r[5] = (f16_t)b.y; r[6] = (f16_t)b.z; r[7] = (f16_t)b.w;
    return r;
}
union U2H4 { uint2 u; f16x4 h; };

// ---------------------------------------------------------------------------
// Permute one 512x512 fp32 slice into MFMA-lane-order fp16 (unchanged).
__global__ __launch_bounds__(256)
void permute_kernel(const float* __restrict__ src, ushort_t* __restrict__ dst)
{
    __shared__ float Lp[16][516];
    const int tid = threadIdx.x;
    const int mc  = blockIdx.x;               // 0..31 row-chunk
    const int s   = blockIdx.y;               // slice
    src += (size_t)s * N_ * N_ + (size_t)mc * 16 * N_;
    uint_t* dstu = (uint_t*)dst + (size_t)s * 131072 + (size_t)mc * 4096;

    #pragma unroll
    for (int k = 0; k < 32; ++k) {
        int idx = tid + 256 * k;
        Lp[idx >> 9][idx & 511] = src[idx];
    }
    __syncthreads();
    #pragma unroll
    for (int k = 0; k < 16; ++k) {
        int u    = tid + 256 * k;
        int nt   = u >> 7;
        int r    = u & 127;
        int quad = r >> 5;
        int cl   = (r >> 1) & 15;
        int m0   = quad * 4 + (r & 1) * 2;
        int n    = nt * 16 + cl;
        union { f16_t h[2]; uint_t i; } pk;
        pk.h[0] = (f16_t)Lp[m0][n];
        pk.h[1] = (f16_t)Lp[m0 + 1][n];
        dstu[u] = pk.i;
    }
}

// ---------------------------------------------------------------------------
// rsinv[b,t,m] = inv_f / sum_n exp(S[m,n]*inv_f). Wave owns one 16-m tile,
// sweeps all 32 n-tiles. No LDS, no barriers, no atomics.
template <int FINAL>
__global__ __launch_bounds__(256)
void rowsum_kernel(const float* __restrict__ x0,
                   const float* __restrict__ xcur,
                   float* __restrict__ rsinv)
{
    const int tid  = threadIdx.x;
    const int w    = tid >> 6;
    const int l    = tid & 63;
    const int quad = l >> 4;
    const int col  = l & 15;
    const int t    = FINAL ? blockIdx.y : blockIdx.y + 1;
    const int b    = blockIdx.z;
    const int mtile = blockIdx.x * 4 + w;           // 0..31
    const float inv_f = 0.17677669529663687f;

    const float* xs = (FINAL && t == 0) ? x0 : xcur;

    f16x8 af = load_frag8(&xs[xidx(b, mtile * 16 + col, t, quad * 8)]);
    f16x8 bf = load_frag8(&xs[xidx(b, col, t, quad * 8)]);   // n-tile 0

    float sw[4] = {0.f, 0.f, 0.f, 0.f};
    for (int nt = 0; nt < 32; ++nt) {
        const int nt2 = (nt < 31) ? nt + 1 : nt;
        f16x8 bf_n = load_frag8(&xs[xidx(b, nt2 * 16 + col, t, quad * 8)]);
        f32x4 s4 = __builtin_amdgcn_mfma_f32_16x16x32_f16(
                       af, bf, (f32x4){0.f, 0.f, 0.f, 0.f}, 0, 0, 0);
        #pragma unroll
        for (int v = 0; v < 4; ++v)
            sw[v] += __expf(fminf(s4[v] * inv_f, 60.f));
        bf = bf_n;
    }
    #pragma unroll
    for (int d = 1; d < 16; d <<= 1)
        #pragma unroll
        for (int v = 0; v < 4; ++v)
            sw[v] += __shfl_xor(sw[v], d, 64);
    if (col < 4) {
        float sv = (col == 0) ? sw[0] : (col == 1) ? sw[1] : (col == 2) ? sw[2] : sw[3];
        rsinv[((size_t)(b * T_ + t)) * N_ + mtile * 16 + quad * 4 + col] =
            inv_f * __builtin_amdgcn_rcpf(sv);
    }
}

// ---------------------------------------------------------------------------
// pred: wave owns 16 n output cols, K-loops all 512 m. Per chunk: score MFMA
// (recompute), W = exp*rsinv*phase(*adj) in regs (C-layout == A-layout), 2
// pred MFMAs. Register accumulate; single store w/ inline mask blend.
template <int FINAL>
__global__ __launch_bounds__(256)
void pred_kernel(const float* __restrict__ x0,
                 const float* __restrict__ xcur,
                 float* __restrict__ dst,           // xnext or agg
                 const ushort_t* __restrict__ phase_h,
                 const ushort_t* __restrict__ adj_h,
                 const float* __restrict__ rsinv,
                 const float* __restrict__ mask)
{
    const int tid  = threadIdx.x;
    const int w    = tid >> 6;
    const int l    = tid & 63;
    const int quad = l >> 4;
    const int col  = l & 15;
    const int t    = FINAL ? blockIdx.y : blockIdx.y + 1;
    const int b    = blockIdx.z;
    const int ntg  = blockIdx.x * 4 + w;            // global n-tile 0..31
    const int n0   = ntg * 16;
    const float inv_f = 0.17677669529663687f;

    const float* xs = (FINAL && t == 0) ? x0 : xcur;
    const float* xp = FINAL ? xs : ((t == 1) ? x0 : xcur);
    const int    tp = FINAL ? t : t - 1;

    // fixed score B-frag: this wave's n rows
    f16x8 bf = load_frag8(&xs[xidx(b, n0 + col, t, quad * 8)]);

    const uint_t* php = (const uint_t*)phase_h + (size_t)(b * T_ + t) * 131072
                        + ntg * 128 + l * 2;
    const uint_t* adp = (const uint_t*)adj_h + ntg * 128 + l * 2;
    const float*  rsv = rsinv + (size_t)(b * T_ + t) * N_;

    // prefetch chunk 0
    f16x8 af = load_frag8(&xs[xidx(b, col, t, quad * 8)]);
    f16x4 bp[2];
    #pragma unroll
    for (int fh = 0; fh < 2; ++fh)
        #pragma unroll
        for (int j = 0; j < 4; ++j)
            bp[fh][j] = (f16_t)xp[xidx(b, quad * 4 + j, tp, fh * 16 + col)];
    uint2 ph = *(const uint2*)php;
    uint2 aj;
    if (FINAL) aj = *(const uint2*)adp;
    f32x4 rs4 = *(const f32x4*)(rsv + quad * 4);

    f32x4 acc0 = (f32x4){0.f, 0.f, 0.f, 0.f};
    f32x4 acc1 = (f32x4){0.f, 0.f, 0.f, 0.f};

    for (int mc = 0; mc < 32; ++mc) {
        // score for this 16-m chunk vs own 16 n
        f32x4 s4 = __builtin_amdgcn_mfma_f32_16x16x32_f16(
                       af, bf, (f32x4){0.f, 0.f, 0.f, 0.f}, 0, 0, 0);

        // prefetch chunk mc+1
        const int mc2 = (mc < 31) ? mc + 1 : mc;
        f16x8 af_n = load_frag8(&xs[xidx(b, mc2 * 16 + col, t, quad * 8)]);
        f16x4 bp_n[2];
        #pragma unroll
        for (int fh = 0; fh < 2; ++fh)
            #pragma unroll
            for (int j = 0; j < 4; ++j)
                bp_n[fh][j] = (f16_t)xp[xidx(b, mc2 * 16 + quad * 4 + j, tp, fh * 16 + col)];
        uint2 ph_n = *(const uint2*)(php + (size_t)mc2 * 4096);
        uint2 aj_n;
        if (FINAL) aj_n = *(const uint2*)(adp + (size_t)mc2 * 4096);
        f32x4 rs4_n = *(const f32x4*)(rsv + mc2 * 16 + quad * 4);

        // W fragment (A-operand of pred MFMA, k = quad*4+v over m)
        U2H4 P; P.u = ph;
        f16x4 wf;
        if (FINAL) {
            U2H4 A; A.u = aj;
            #pragma unroll
            for (int v = 0; v < 4; ++v)
                wf[v] = (f16_t)(__expf(fminf(s4[v] * inv_f, 60.f)) * rs4[v]
                                * (float)P.h[v] * (float)A.h[v]);
        } else {
            #pragma unroll
            for (int v = 0; v < 4; ++v)
                wf[v] = (f16_t)(__expf(fminf(s4[v] * inv_f, 60.f)) * rs4[v]
                                * (float)P.h[v]);
        }
        acc0 = __builtin_amdgcn_mfma_f32_16x16x16f16(wf, bp[0], acc0, 0, 0, 0);
        acc1 = __builtin_amdgcn_mfma_f32_16x16x16f16(wf, bp[1], acc1, 0, 0, 0);

        af = af_n; bp[0] = bp_n[0]; bp[1] = bp_n[1];
        ph = ph_n; rs4 = rs4_n;
        if (FINAL) aj = aj_n;
    }

    // epilogue: lane holds Y[n = n0+quad*4+v][f = col / col+16]; single writer
    #pragma unroll
    for (int v = 0; v < 4; ++v) {
        const int n = n0 + quad * 4 + v;
        float p0 = acc0[v], p1 = acc1[v];
        if (FINAL) {
            float* d0 = &dst[((size_t)(b * T_ + t) * N_ + n) * F_ + col];
            d0[0]  = p0;
            d0[16] = p1;
        } else {
            if (mask[n] != 0.f) {           // masked node: passthrough
                p0 = xcur[xidx(b, n, t, col)];
                p1 = xcur[xidx(b, n, t, col + 16)];
            }
            dst[xidx(b, n, t, col)]      = p0;
            dst[xidx(b, n, t, col + 16)] = p1;
        }
    }
}

// out[b,n,t,o] = relu(sum_f agg[b,t,n,f] * theta[f,o])
__global__ __launch_bounds__(256)
void proj_kernel(const float* __restrict__ agg, const float* __restrict__ theta,
                 float* __restrict__ out)
{
    __shared__ float th[F_ * O_];
    int tid = threadIdx.x;
    #pragma unroll
    for (int p = 0; p < 8; ++p) th[tid + 256 * p] = theta[tid + 256 * p];
    __syncthreads();
    int g  = blockIdx.x * 256 + tid;               // ((b*N+n)*T+t)*O+o
    int o  = g & 63;
    int r  = g >> 6;
    int tt = r % T_;
    int r2 = r / T_;
    int n  = r2 & 511;
    int b  = r2 >> 9;
    const float* a = &agg[((b * T_ + tt) * N_ + n) * F_];
    float s = 0.f;
    #pragma unroll
    for (int f = 0; f < F_; ++f) s += a[f] * th[f * O_ + o];
    out[g] = fmaxf(s, 0.f);
}

extern "C" void kernel_launch(void* const* d_in, const int* in_sizes, int n_in,
                              void* d_out, int out_size, void* d_ws, size_t ws_size,
                              hipStream_t stream)
{
    const float* x     = (const float*)d_in[0];
    const float* phase = (const float*)d_in[1];
    const float* adj   = (const float*)d_in[2];
    const float* mask  = (const float*)d_in[3];
    const float* theta = (const float*)d_in[4];
    float* out = (float*)d_out;

    const size_t XE = (size_t)B_ * N_ * T_ * F_;        // 1,572,864 floats
    float*    bufs    = (float*)d_ws;                   // 11 iter outputs
    float*    agg     = bufs + (size_t)11 * XE;
    ushort_t* phase_h = (ushort_t*)(bufs + (size_t)12 * XE);  // 96 slices f16
    ushort_t* adj_h   = phase_h + (size_t)96 * N_ * N_;
    float*    rs      = (float*)(adj_h + (size_t)N_ * N_);    // 96*512 floats

    permute_kernel<<<dim3(32, 96), 256, 0, stream>>>(phase, phase_h);
    permute_kernel<<<dim3(32, 1), 256, 0, stream>>>(adj, adj_h);

    const float* cur = x;
    for (int i = 0; i < T_ - 1; ++i) {                  // 11 Jacobi iterations
        float* nxt = bufs + (size_t)i * XE;
        rowsum_kernel<0><<<dim3(8, T_ - 1, B_), 256, 0, stream>>>(x, cur, rs);
        pred_kernel<0><<<dim3(8, T_ - 1, B_), 256, 0, stream>>>(
            x, cur, nxt, phase_h, adj_h, rs, mask);
        cur = nxt;
    }
    rowsum_kernel<1><<<dim3(8, T_, B_), 256, 0, stream>>>(x, cur, rs);
    pred_kernel<1><<<dim3(8, T_, B_), 256, 0, stream>>>(
        x, cur, agg, phase_h, adj_h, rs, mask);
    proj_kernel<<<(B_ * N_ * T_ * O_) / 256, 256, 0, stream>>>(agg, theta, out);
}

// Round 7
// 897.690 us; speedup vs baseline: 1.7853x; 1.2019x over previous
//
#include <hip/hip_runtime.h>

// spatialAttentionScaledGCN — MI355X MFMA, round 7: phase-streaming concurrency.
// B=8, N=512, T=12, F=32, O=64. All I/O fp32.
// vs R6: (a) phase repacked pair-interleaved so each lane loads 16B (dwordx4)
// covering 2 m-chunks; (b) phase prefetch 2 pairs (4 chunks) deep → ~2KB/wave
// in flight (full-BW concurrency); (c) grid = (slice, ngroup), gridDim.x ≡ 0
// mod 8 → slice pinned to one XCD (L2 reuse across the 12 passes).
// Still zero atomics / zero LDS in the iteration kernels.

#define B_ 8
#define N_ 512
#define T_ 12
#define F_ 32
#define O_ 64

typedef unsigned int uint_t;
typedef unsigned short ushort_t;
typedef _Float16 f16_t;
typedef _Float16 f16x4 __attribute__((ext_vector_type(4)));
typedef _Float16 f16x8 __attribute__((ext_vector_type(8)));
typedef float f32x4 __attribute__((ext_vector_type(4)));

__device__ __forceinline__ int xidx(int b, int n, int t, int f) {
    return ((b * N_ + n) * T_ + t) * F_ + f;
}
__device__ __forceinline__ f16x8 load_frag8(const float* p) {
    float4 a = *reinterpret_cast<const float4*>(p);
    float4 b = *reinterpret_cast<const float4*>(p + 4);
    f16x8 r;
    r[0] = (f16_t)a.x; r[1] = (f16_t)a.y; r[2] = (f16_t)a.z; r[3] = (f16_t)a.w;
    r[4] = (f16_t)b.x; r[5] = (f16_t)b.y; r[6] = (f16_t)b.z; r[7] = (f16_t)b.w;
    return r;
}
union U2H4 { uint2 u; f16x4 h; };

// ---------------------------------------------------------------------------
// Permute one 512x512 fp32 slice into pair-interleaved MFMA-lane-order fp16:
// uint index = (mc>>1)*8192 + nt*256 + lane*4 + (mc&1)*2 + vp
// so consuming lane reads ONE dwordx4 per m-chunk-pair.
__global__ __launch_bounds__(256)
void permute_kernel(const float* __restrict__ src, ushort_t* __restrict__ dst)
{
    __shared__ float Lp[16][516];
    const int tid = threadIdx.x;
    const int mc  = blockIdx.x;               // 0..31 row-chunk (16 m-rows)
    const int s   = blockIdx.y;               // slice
    src += (size_t)s * N_ * N_ + (size_t)mc * 16 * N_;
    uint_t* dstu = (uint_t*)dst + (size_t)s * 131072;

    #pragma unroll
    for (int k = 0; k < 32; ++k) {
        int idx = tid + 256 * k;
        Lp[idx >> 9][idx & 511] = src[idx];
    }
    __syncthreads();
    #pragma unroll
    for (int k = 0; k < 16; ++k) {
        int u    = tid + 256 * k;             // 0..4095
        int nt   = u >> 7;                    // n-tile 0..31
        int r    = u & 127;
        int quad = r >> 5;
        int cl   = (r >> 1) & 15;
        int vp   = r & 1;                     // which v-pair
        int m0   = quad * 4 + vp * 2;
        int n    = nt * 16 + cl;
        int lane = quad * 16 + cl;
        union { f16_t h[2]; uint_t i; } pk;
        pk.h[0] = (f16_t)Lp[m0][n];
        pk.h[1] = (f16_t)Lp[m0 + 1][n];
        dstu[(mc >> 1) * 8192 + nt * 256 + lane * 4 + (mc & 1) * 2 + vp] = pk.i;
    }
}

// ---------------------------------------------------------------------------
// rsinv[b,t,m] = inv_f / sum_n exp(S[m,n]*inv_f). Wave owns one 16-m tile.
// Grid (NS, 8): slice-major for XCD affinity.
template <int FINAL>
__global__ __launch_bounds__(256)
void rowsum_kernel(const float* __restrict__ x0,
                   const float* __restrict__ xcur,
                   float* __restrict__ rsinv)
{
    const int tid  = threadIdx.x;
    const int w    = tid >> 6;
    const int l    = tid & 63;
    const int quad = l >> 4;
    const int col  = l & 15;
    const int s    = blockIdx.x;
    const int t    = FINAL ? (s % T_) : (s % (T_ - 1)) + 1;
    const int b    = FINAL ? (s / T_) : (s / (T_ - 1));
    const int mtile = blockIdx.y * 4 + w;           // 0..31
    const float inv_f = 0.17677669529663687f;

    const float* xs = (FINAL && t == 0) ? x0 : xcur;

    f16x8 af = load_frag8(&xs[xidx(b, mtile * 16 + col, t, quad * 8)]);
    f16x8 bf = load_frag8(&xs[xidx(b, col, t, quad * 8)]);   // n-tile 0

    float sw[4] = {0.f, 0.f, 0.f, 0.f};
    for (int nt = 0; nt < 32; ++nt) {
        const int nt2 = (nt < 31) ? nt + 1 : nt;
        f16x8 bf_n = load_frag8(&xs[xidx(b, nt2 * 16 + col, t, quad * 8)]);
        f32x4 s4 = __builtin_amdgcn_mfma_f32_16x16x32_f16(
                       af, bf, (f32x4){0.f, 0.f, 0.f, 0.f}, 0, 0, 0);
        #pragma unroll
        for (int v = 0; v < 4; ++v)
            sw[v] += __expf(fminf(s4[v] * inv_f, 60.f));
        bf = bf_n;
    }
    #pragma unroll
    for (int d = 1; d < 16; d <<= 1)
        #pragma unroll
        for (int v = 0; v < 4; ++v)
            sw[v] += __shfl_xor(sw[v], d, 64);
    if (col < 4) {
        float sv = (col == 0) ? sw[0] : (col == 1) ? sw[1] : (col == 2) ? sw[2] : sw[3];
        rsinv[((size_t)(b * T_ + t)) * N_ + mtile * 16 + quad * 4 + col] =
            inv_f * __builtin_amdgcn_rcpf(sv);
    }
}

// ---------------------------------------------------------------------------
// pred: wave owns 16 output n-cols, K-loops all 512 m as 16 chunk-pairs.
// Per pair: 1 dwordx4 phase load (2 chunks), prefetched 2 pairs deep.
template <int FINAL>
__global__ __launch_bounds__(256)
void pred_kernel(const float* __restrict__ x0,
                 const float* __restrict__ xcur,
                 float* __restrict__ dst,           // xnext or agg
                 const ushort_t* __restrict__ phase_h,
                 const ushort_t* __restrict__ adj_h,
                 const float* __restrict__ rsinv,
                 const float* __restrict__ mask)
{
    const int tid  = threadIdx.x;
    const int w    = tid >> 6;
    const int l    = tid & 63;
    const int quad = l >> 4;
    const int col  = l & 15;
    const int s    = blockIdx.x;
    const int t    = FINAL ? (s % T_) : (s % (T_ - 1)) + 1;
    const int b    = FINAL ? (s / T_) : (s / (T_ - 1));
    const int ntg  = blockIdx.y * 4 + w;            // n-tile 0..31
    const int n0   = ntg * 16;
    const float inv_f = 0.17677669529663687f;

    const float* xs = (FINAL && t == 0) ? x0 : xcur;
    const float* xp = FINAL ? xs : ((t == 1) ? x0 : xcur);
    const int    tp = FINAL ? t : t - 1;

    // fixed score B-frag: this wave's n rows
    f16x8 bf = load_frag8(&xs[xidx(b, n0 + col, t, quad * 8)]);

    const uint4* php = (const uint4*)((const uint_t*)phase_h
                        + (size_t)(b * T_ + t) * 131072) + ntg * 64 + l;
    const uint4* adp = (const uint4*)(const uint_t*)adj_h + ntg * 64 + l;
    const float* rsv = rsinv + (size_t)(b * T_ + t) * N_;

    // phase pipeline: 2 pairs in flight
    uint4 PH0 = php[0];
    uint4 PH1 = php[2048];
    uint4 AJ0, AJ1;
    if (FINAL) { AJ0 = adp[0]; AJ1 = adp[2048]; }

    // x/rs pipeline: current pair's operands
    f16x8 af[2];
    f16x4 bp[2][2];
    f32x4 rs[2];
    #pragma unroll
    for (int q = 0; q < 2; ++q) {
        af[q] = load_frag8(&xs[xidx(b, q * 16 + col, t, quad * 8)]);
        #pragma unroll
        for (int fh = 0; fh < 2; ++fh)
            #pragma unroll
            for (int j = 0; j < 4; ++j)
                bp[q][fh][j] = (f16_t)xp[xidx(b, q * 16 + quad * 4 + j, tp, fh * 16 + col)];
        rs[q] = *(const f32x4*)(rsv + q * 16 + quad * 4);
    }

    f32x4 acc0 = (f32x4){0.f, 0.f, 0.f, 0.f};
    f32x4 acc1 = (f32x4){0.f, 0.f, 0.f, 0.f};

    for (int p = 0; p < 16; ++p) {
        // prefetch phase pair p+2 and x/rs pair p+1
        const int pf2 = (p < 14) ? p + 2 : p;
        uint4 PHn = php[(size_t)pf2 * 2048];
        uint4 AJn;
        if (FINAL) AJn = adp[(size_t)pf2 * 2048];

        const int p1 = (p < 15) ? p + 1 : p;
        f16x8 af_n[2];
        f16x4 bp_n[2][2];
        f32x4 rs_n[2];
        #pragma unroll
        for (int q = 0; q < 2; ++q) {
            const int mb = (p1 * 2 + q) * 16;
            af_n[q] = load_frag8(&xs[xidx(b, mb + col, t, quad * 8)]);
            #pragma unroll
            for (int fh = 0; fh < 2; ++fh)
                #pragma unroll
                for (int j = 0; j < 4; ++j)
                    bp_n[q][fh][j] = (f16_t)xp[xidx(b, mb + quad * 4 + j, tp, fh * 16 + col)];
            rs_n[q] = *(const f32x4*)(rsv + mb + quad * 4);
        }

        // compute the two chunks of pair p
        #pragma unroll
        for (int q = 0; q < 2; ++q) {
            f32x4 s4 = __builtin_amdgcn_mfma_f32_16x16x32_f16(
                           af[q], bf, (f32x4){0.f, 0.f, 0.f, 0.f}, 0, 0, 0);
            U2H4 P;
            P.u = q ? make_uint2(PH0.z, PH0.w) : make_uint2(PH0.x, PH0.y);
            f16x4 wf;
            if (FINAL) {
                U2H4 A;
                A.u = q ? make_uint2(AJ0.z, AJ0.w) : make_uint2(AJ0.x, AJ0.y);
                #pragma unroll
                for (int v = 0; v < 4; ++v)
                    wf[v] = (f16_t)(__expf(fminf(s4[v] * inv_f, 60.f)) * rs[q][v]
                                    * (float)P.h[v] * (float)A.h[v]);
            } else {
                #pragma unroll
                for (int v = 0; v < 4; ++v)
                    wf[v] = (f16_t)(__expf(fminf(s4[v] * inv_f, 60.f)) * rs[q][v]
                                    * (float)P.h[v]);
            }
            acc0 = __builtin_amdgcn_mfma_f32_16x16x16f16(wf, bp[q][0], acc0, 0, 0, 0);
            acc1 = __builtin_amdgcn_mfma_f32_16x16x16f16(wf, bp[q][1], acc1, 0, 0, 0);
        }

        PH0 = PH1; PH1 = PHn;
        if (FINAL) { AJ0 = AJ1; AJ1 = AJn; }
        #pragma unroll
        for (int q = 0; q < 2; ++q) {
            af[q] = af_n[q];
            bp[q][0] = bp_n[q][0]; bp[q][1] = bp_n[q][1];
            rs[q] = rs_n[q];
        }
    }

    // epilogue: lane holds Y[n = n0+quad*4+v][f = col / col+16]; single writer
    #pragma unroll
    for (int v = 0; v < 4; ++v) {
        const int n = n0 + quad * 4 + v;
        float p0 = acc0[v], p1 = acc1[v];
        if (FINAL) {
            float* d0 = &dst[((size_t)(b * T_ + t) * N_ + n) * F_ + col];
            d0[0]  = p0;
            d0[16] = p1;
        } else {
            if (mask[n] != 0.f) {           // masked node: passthrough
                p0 = xcur[xidx(b, n, t, col)];
                p1 = xcur[xidx(b, n, t, col + 16)];
            }
            dst[xidx(b, n, t, col)]      = p0;
            dst[xidx(b, n, t, col + 16)] = p1;
        }
    }
}

// out[b,n,t,o] = relu(sum_f agg[b,t,n,f] * theta[f,o])
__global__ __launch_bounds__(256)
void proj_kernel(const float* __restrict__ agg, const float* __restrict__ theta,
                 float* __restrict__ out)
{
    __shared__ float th[F_ * O_];
    int tid = threadIdx.x;
    #pragma unroll
    for (int p = 0; p < 8; ++p) th[tid + 256 * p] = theta[tid + 256 * p];
    __syncthreads();
    int g  = blockIdx.x * 256 + tid;               // ((b*N+n)*T+t)*O+o
    int o  = g & 63;
    int r  = g >> 6;
    int tt = r % T_;
    int r2 = r / T_;
    int n  = r2 & 511;
    int b  = r2 >> 9;
    const float* a = &agg[((b * T_ + tt) * N_ + n) * F_];
    float s = 0.f;
    #pragma unroll
    for (int f = 0; f < F_; ++f) s += a[f] * th[f * O_ + o];
    out[g] = fmaxf(s, 0.f);
}

extern "C" void kernel_launch(void* const* d_in, const int* in_sizes, int n_in,
                              void* d_out, int out_size, void* d_ws, size_t ws_size,
                              hipStream_t stream)
{
    const float* x     = (const float*)d_in[0];
    const float* phase = (const float*)d_in[1];
    const float* adj   = (const float*)d_in[2];
    const float* mask  = (const float*)d_in[3];
    const float* theta = (const float*)d_in[4];
    float* out = (float*)d_out;

    const size_t XE = (size_t)B_ * N_ * T_ * F_;        // 1,572,864 floats
    float*    bufs    = (float*)d_ws;                   // 11 iter outputs
    float*    agg     = bufs + (size_t)11 * XE;
    ushort_t* phase_h = (ushort_t*)(bufs + (size_t)12 * XE);  // 96 slices f16
    ushort_t* adj_h   = phase_h + (size_t)96 * N_ * N_;
    float*    rs      = (float*)(adj_h + (size_t)N_ * N_);    // 96*512 floats

    permute_kernel<<<dim3(32, 96), 256, 0, stream>>>(phase, phase_h);
    permute_kernel<<<dim3(32, 1), 256, 0, stream>>>(adj, adj_h);

    const int NS_IT = B_ * (T_ - 1);                    // 88 ≡ 0 mod 8
    const int NS_FN = B_ * T_;                          // 96 ≡ 0 mod 8
    const float* cur = x;
    for (int i = 0; i < T_ - 1; ++i) {                  // 11 Jacobi iterations
        float* nxt = bufs + (size_t)i * XE;
        rowsum_kernel<0><<<dim3(NS_IT, 8), 256, 0, stream>>>(x, cur, rs);
        pred_kernel<0><<<dim3(NS_IT, 8), 256, 0, stream>>>(
            x, cur, nxt, phase_h, adj_h, rs, mask);
        cur = nxt;
    }
    rowsum_kernel<1><<<dim3(NS_FN, 8), 256, 0, stream>>>(x, cur, rs);
    pred_kernel<1><<<dim3(NS_FN, 8), 256, 0, stream>>>(
        x, cur, agg, phase_h, adj_h, rs, mask);
    proj_kernel<<<(B_ * N_ * T_ * O_) / 256, 256, 0, stream>>>(agg, theta, out);
}